// Round 6
// baseline (130.576 us; speedup 1.0000x reference)
//
#include <hip/hip_runtime.h>
#include <cstdint>

typedef __bf16 bf16x8 __attribute__((ext_vector_type(8)));
typedef __bf16 bf16x4 __attribute__((ext_vector_type(4)));
typedef float  f32x4  __attribute__((ext_vector_type(4)));

static constexpr int kB = 2, kT = 2048, kC = 1024, kH = 16, kD = 64;
static constexpr int kK = 1024;  // GEMM inner dim (= kC)

__device__ __forceinline__ uint16_t f2bf(float f) {
  uint32_t u = __builtin_bit_cast(uint32_t, f);
  u += 0x7FFFu + ((u >> 16) & 1u);
  return (uint16_t)(u >> 16);
}

__device__ __forceinline__ void gl_lds16(const void* g, void* l) {
  __builtin_amdgcn_global_load_lds((__attribute__((address_space(1))) void*)(void*)g,
                                   (__attribute__((address_space(3))) void*)l, 16, 0, 0);
}

// ---------------- fused prep: xp = bf16(x+pe); w casts ----------------
__global__ __launch_bounds__(256) void prep_all(const float* __restrict__ x,
                                                const float* __restrict__ pe,
                                                const float* __restrict__ wqkv,
                                                const float* __restrict__ wproj,
                                                uint16_t* __restrict__ xp,
                                                uint16_t* __restrict__ wq,
                                                uint16_t* __restrict__ wp) {
  constexpr int NX = kB * kT * kC / 4;   // 1048576
  constexpr int NWQ = 3 * kC * kC / 4;   // 786432
  const int i = blockIdx.x * 256 + threadIdx.x;
  if (i < NX) {
    const float4 xv = ((const float4*)x)[i];
    const int c4 = i & (kC / 4 - 1);
    const int t = (i / (kC / 4)) & (kT - 1);
    const float4 pv = ((const float4*)pe)[t * (kC / 4) + c4];
    ushort4 o;
    o.x = f2bf(xv.x + pv.x);
    o.y = f2bf(xv.y + pv.y);
    o.z = f2bf(xv.z + pv.z);
    o.w = f2bf(xv.w + pv.w);
    ((ushort4*)xp)[i] = o;
  } else if (i < NX + NWQ) {
    const int j = i - NX;
    const float4 v = ((const float4*)wqkv)[j];
    ushort4 u;
    u.x = f2bf(v.x); u.y = f2bf(v.y); u.z = f2bf(v.z); u.w = f2bf(v.w);
    ((ushort4*)wq)[j] = u;
  } else {
    const int j = i - NX - NWQ;
    const float4 v = ((const float4*)wproj)[j];
    ushort4 u;
    u.x = f2bf(v.x); u.y = f2bf(v.y); u.z = f2bf(v.z); u.w = f2bf(v.w);
    ((ushort4*)wp)[j] = u;
  }
}

// ---------------- QKV GEMM: 256x192 tile, 4-phase counted-vmcnt ----------------
// M=4096 N=3072 K=1024 -> 16x16 = 256 blocks (100% CU). 8 waves 4Mx2N,
// wave-tile 64x96. Iter = 2 K-tiles (buf0/buf1); phase = K-tile x col-half;
// A-frags read once per K-tile, reused across both col-half phases.
// Stages: p0 A1(2i+1), p1 B1(2i+1), p2 A0(2i+2), p3 B0(2i+2); vmcnt(4)@p0,p2.
__global__ __launch_bounds__(512, 2) void gemm_qkv(const uint16_t* __restrict__ A,
                                                   const uint16_t* __restrict__ W,
                                                   uint16_t* __restrict__ qb,
                                                   uint16_t* __restrict__ kb,
                                                   uint16_t* __restrict__ vT) {
  __shared__ __align__(1024) char lds[114688];  // A: 2x32K @0 | B: 2x24K @65536
  const int tid = threadIdx.x;
  const int lane = tid & 63;
  const int l15 = lane & 15, l4 = lane >> 4;
  const int wid = tid >> 6;
  const int WM = wid >> 1, WN = wid & 1;
  const int orig = (int)blockIdx.x;
  const int xcd = orig & 7, j = orig >> 3;
  const int m0 = (xcd * 2 + (j & 1)) * 256;  // 16 m-tiles
  const int n0 = (j >> 1) * 192;             // 16 n-tiles

  f32x4 acc[4][6] = {};  // [mt][qc*3+ntl]

  auto stageA = [&](int buf, int kt) {
#pragma unroll
    for (int c = 0; c < 4; ++c) {
      const int off = (c * 512 + tid) * 16;
      const int lr = off >> 7, cbl = off & 127;
      gl_lds16((const char*)A + ((size_t)(m0 + lr) * kK + kt * 64) * 2 +
                   (cbl ^ ((lr & 7) << 4)),
               lds + buf * 32768 + off);
    }
  };
  auto stageB = [&](int buf, int kt) {
#pragma unroll
    for (int c = 0; c < 3; ++c) {
      const int off = (c * 512 + tid) * 16;
      const int lr = off >> 7, cbl = off & 127;
      gl_lds16((const char*)W + ((size_t)(n0 + lr) * kK + kt * 64) * 2 +
                   (cbl ^ ((lr & 7) << 4)),
               lds + 65536 + buf * 24576 + off);
    }
  };

  bf16x8 af[2][4], bfr[2][3];
  auto readA = [&](int buf) {
#pragma unroll
    for (int ks = 0; ks < 2; ++ks)
#pragma unroll
      for (int mt = 0; mt < 4; ++mt) {
        const int r = WM * 64 + mt * 16 + l15;
        af[ks][mt] = *(const bf16x8*)(lds + buf * 32768 + r * 128 +
                                      ((ks * 64 + l4 * 16) ^ ((r & 7) << 4)));
      }
  };
  auto readB = [&](int buf, int qc) {
#pragma unroll
    for (int ks = 0; ks < 2; ++ks)
#pragma unroll
      for (int ntl = 0; ntl < 3; ++ntl) {
        const int r = WN * 96 + qc * 48 + ntl * 16 + l15;
        bfr[ks][ntl] = *(const bf16x8*)(lds + 65536 + buf * 24576 + r * 128 +
                                        ((ks * 64 + l4 * 16) ^ ((r & 7) << 4)));
      }
  };
  auto mfma6 = [&](int qc) {
    __builtin_amdgcn_s_setprio(1);
#pragma unroll
    for (int ks = 0; ks < 2; ++ks)
#pragma unroll
      for (int mt = 0; mt < 4; ++mt)
#pragma unroll
        for (int ntl = 0; ntl < 3; ++ntl)
          acc[mt][qc * 3 + ntl] = __builtin_amdgcn_mfma_f32_16x16x32_bf16(
              af[ks][mt], bfr[ks][ntl], acc[mt][qc * 3 + ntl], 0, 0, 0);
    __builtin_amdgcn_s_setprio(0);
  };

  // prologue: buf0 <- kt 0
  stageA(0, 0);
  stageB(0, 0);

  for (int i = 0; i < 8; ++i) {
    int ktn = 2 * i + 2;
    if (ktn > 15) ktn = 15;  // clamp, never skip (vmcnt arithmetic)
    // p0
    stageA(1, 2 * i + 1);
    asm volatile("s_waitcnt vmcnt(4)" ::: "memory");
    __builtin_amdgcn_s_barrier();
    asm volatile("" ::: "memory");
    readA(0); readB(0, 0); mfma6(0);
    // p1
    stageB(1, 2 * i + 1);
    readB(0, 1); mfma6(1);
    asm volatile("" ::: "memory");
    __builtin_amdgcn_s_barrier();
    asm volatile("" ::: "memory");
    // p2
    stageA(0, ktn);
    asm volatile("s_waitcnt vmcnt(4)" ::: "memory");
    __builtin_amdgcn_s_barrier();
    asm volatile("" ::: "memory");
    readA(1); readB(1, 0); mfma6(0 + 0);  // qc0 of kt=2i+1 accumulates same acc cols
    // NOTE: acc is summed over K, so qc index only selects columns:
    // p2 is qc=0, p3 is qc=1 (same as p0/p1).
    // p3
    stageB(0, ktn);
    readB(1, 1); mfma6(1);
    asm volatile("" ::: "memory");
    __builtin_amdgcn_s_barrier();
    asm volatile("" ::: "memory");
  }

  // ---- epilogue: per-element q/k/v routing (2B stores; proven adequate) ----
  const int b = m0 >> 11, tb = m0 & (kT - 1);
#pragma unroll
  for (int mt = 0; mt < 4; ++mt)
#pragma unroll
    for (int qc = 0; qc < 2; ++qc)
#pragma unroll
      for (int ntl = 0; ntl < 3; ++ntl)
#pragma unroll
        for (int r = 0; r < 4; ++r) {
          const int m = WM * 64 + mt * 16 + l4 * 4 + r;
          const int t = tb + m;
          const int n = n0 + WN * 96 + qc * 48 + ntl * 16 + l15;
          const int sec = n >> 10, nn = n & (kC - 1);
          const int h = nn >> 6, d = nn & 63;
          const uint16_t v = f2bf(acc[mt][qc * 3 + ntl][r]);
          if (sec == 0)
            qb[((size_t)((b * kH + h) * kT + t)) * kD + d] = v;
          else if (sec == 1)
            kb[((size_t)((b * kH + h) * kT + t)) * kD + d] = v;
          else
            vT[((size_t)((b * kH + h) * kD + d)) * kT + t] = v;
        }
}

// ---------------- proj GEMM: C = A[M,K] * W[N,K]^T, f32 out (128^2) ----------
__global__ __launch_bounds__(256) void gemm_proj(const uint16_t* __restrict__ A,
                                                 const uint16_t* __restrict__ W,
                                                 float* __restrict__ out) {
  __shared__ __align__(1024) char lds[32768];
  const int lane = threadIdx.x & 63;
  const int wid = threadIdx.x >> 6;
  const int l15 = lane & 15, l4 = lane >> 4;
  const int wm = wid >> 1, wn = wid & 1;
  const int orig = (int)(blockIdx.y * gridDim.x + blockIdx.x);
  const int xcd = orig & 7, j = orig >> 3;
  const int m0 = (xcd * 4 + (j & 3)) * 128;
  const int n0 = (j >> 2) * 128;

  f32x4 acc[4][4] = {};

  for (int k0 = 0; k0 < kK; k0 += 64) {
#pragma unroll
    for (int jj = 0; jj < 4; ++jj) {
      const int off = wid * 4096 + jj * 1024 + lane * 16;
      const int row = off >> 7;
      const int colb = (off & 127) ^ ((row & 7) << 4);
      gl_lds16((const char*)A + ((size_t)(m0 + row) * kK + k0) * 2 + colb,
               lds + wid * 4096 + jj * 1024);
      gl_lds16((const char*)W + ((size_t)(n0 + row) * kK + k0) * 2 + colb,
               lds + 16384 + wid * 4096 + jj * 1024);
    }
    __syncthreads();
#pragma unroll
    for (int ks = 0; ks < 2; ++ks) {
      bf16x8 af[4], bf_[4];
#pragma unroll
      for (int mt = 0; mt < 4; ++mt) {
        const int r = wm * 64 + mt * 16 + l15;
        const int cb = (l4 * 16 + ks * 64) ^ ((r & 7) << 4);
        af[mt] = *(const bf16x8*)(lds + r * 128 + cb);
      }
#pragma unroll
      for (int nt = 0; nt < 4; ++nt) {
        const int r = wn * 64 + nt * 16 + l15;
        const int cb = (l4 * 16 + ks * 64) ^ ((r & 7) << 4);
        bf_[nt] = *(const bf16x8*)(lds + 16384 + r * 128 + cb);
      }
#pragma unroll
      for (int mt = 0; mt < 4; ++mt)
#pragma unroll
        for (int nt = 0; nt < 4; ++nt)
          acc[mt][nt] = __builtin_amdgcn_mfma_f32_16x16x32_bf16(af[mt], bf_[nt],
                                                                acc[mt][nt], 0, 0, 0);
    }
    __syncthreads();
  }

#pragma unroll
  for (int mt = 0; mt < 4; ++mt)
#pragma unroll
    for (int nt = 0; nt < 4; ++nt)
#pragma unroll
      for (int r = 0; r < 4; ++r) {
        const int m = m0 + wm * 64 + mt * 16 + l4 * 4 + r;
        const int n = n0 + wn * 64 + nt * 16 + l15;
        out[(size_t)m * kC + n] = acc[mt][nt][r];
      }
}

// ---------------- flash attention (causal), swapped-QK, 32 q-rows/wave --------
// Block = 4 waves x 32 rows = 128 q-rows; K/V frag reads shared across the two
// 16-row halves (halves LDS read traffic per MFMA). Shifted-domain softmax:
// MFMA C-init = -m so defer path needs no subtract. grid(x=bh, y=qt'),
// qt = 15 - y (LPT); XCD ~ bh%8 clusters K/V in L2.
__global__ __launch_bounds__(256, 3) void attn(const uint16_t* __restrict__ qb,
                                               const uint16_t* __restrict__ kb,
                                               const uint16_t* __restrict__ vT,
                                               uint16_t* __restrict__ y) {
  // LDS: K[2] @ 0/8192 | V[2] @ 16384/24576 | P @ 32768 + wid*4096 + h*2048
  __shared__ __align__(1024) char lds[49152];
  const int lane = threadIdx.x & 63;
  const int wid = threadIdx.x >> 6;
  const int l15 = lane & 15, l4 = lane >> 4;
  const int bh = blockIdx.x;
  const int qt = (int)(gridDim.y - 1) - (int)blockIdx.y;
  const int q0w = qt * 128 + wid * 32;  // this wave's first q row
  const size_t base = (size_t)bh * kT * kD;
  const uint16_t* Q = qb + base;
  const uint16_t* Kp = kb + base;
  const uint16_t* Vt = vT + base;
  char* P = lds + 32768 + wid * 4096;
  const int xr = (l15 & 7) << 4;

  // Q fragments, scaled by log2(e)/sqrt(d) (exp2-domain softmax)
  bf16x8 qf[2][2];
#pragma unroll
  for (int h = 0; h < 2; ++h)
#pragma unroll
    for (int ks = 0; ks < 2; ++ks) {
      bf16x8 t = *(const bf16x8*)(Q + (size_t)(q0w + h * 16 + l15) * kD + ks * 32 + l4 * 8);
#pragma unroll
      for (int i = 0; i < 8; ++i) t[i] = (__bf16)((float)t[i] * 0.1803368801f);
      qf[h][ks] = t;
    }

  float m_[2] = {0.f, 0.f}, l_[2] = {0.f, 0.f};  // shifted-domain; m_ row-uniform
  f32x4 o[2][4] = {};  // O^T[d = nt*16 + l4*4 + r][q = l15] per half

  const int nkt = 2 * qt + 2;      // block-uniform tile count
  const int qwmax = q0w + 31;      // wave's last q row

  auto STAGE = [&](int bi, int k0) {
#pragma unroll
    for (int c = 0; c < 2; ++c) {
      const int call = wid * 2 + c;
      const int row = call * 8 + (lane >> 3);
      const int colb = (((lane & 7) ^ ((lane >> 3) & 7)) << 4);
      gl_lds16((const char*)Kp + ((size_t)(k0 + row) * kD) * 2 + colb,
               lds + bi * 8192 + call * 1024);
      gl_lds16((const char*)Vt + ((size_t)row * kT + k0) * 2 + colb,
               lds + 16384 + bi * 8192 + call * 1024);
    }
  };

  int cur = 0;
  STAGE(0, 0);
  for (int kt = 0; kt < nkt; ++kt) {
    const int k0 = kt * 64;
    const bool hasnext = (kt + 1 < nkt);
    if (hasnext) STAGE(cur ^ 1, k0 + 64);
    if (hasnext)
      asm volatile("s_waitcnt vmcnt(4)" ::: "memory");
    else
      asm volatile("s_waitcnt vmcnt(0)" ::: "memory");
    __builtin_amdgcn_s_barrier();
    asm volatile("" ::: "memory");

    if (k0 <= qwmax) {  // wave-level skip of fully-masked tiles (barriers kept)
      const char* Kb = lds + cur * 8192;
      const char* Vb = lds + 16384 + cur * 8192;

      // S' = K Q^T - m  (shifted log2-domain; C-init = -m)
      f32x4 s[2][4];
#pragma unroll
      for (int h = 0; h < 2; ++h)
#pragma unroll
        for (int nt = 0; nt < 4; ++nt)
          s[h][nt] = (f32x4){-m_[h], -m_[h], -m_[h], -m_[h]};
      __builtin_amdgcn_s_setprio(1);
#pragma unroll
      for (int ks = 0; ks < 2; ++ks)
#pragma unroll
        for (int nt = 0; nt < 4; ++nt) {
          const bf16x8 kf =
              *(const bf16x8*)(Kb + (nt * 16 + l15) * 128 + ((ks * 64 + l4 * 16) ^ xr));
          s[0][nt] = __builtin_amdgcn_mfma_f32_16x16x32_bf16(kf, qf[0][ks], s[0][nt], 0, 0, 0);
          s[1][nt] = __builtin_amdgcn_mfma_f32_16x16x32_bf16(kf, qf[1][ks], s[1][nt], 0, 0, 0);
        }
      __builtin_amdgcn_s_setprio(0);

      // causal mask + softmax per half
#pragma unroll
      for (int h = 0; h < 2; ++h) {
        if (k0 + 63 > q0w + h * 16) {
          const int qq = q0w + h * 16 + l15;
#pragma unroll
          for (int nt = 0; nt < 4; ++nt)
#pragma unroll
            for (int r = 0; r < 4; ++r)
              if (k0 + nt * 16 + l4 * 4 + r > qq) s[h][nt][r] = -1e30f;
        }
        float pm = s[h][0][0];
#pragma unroll
        for (int nt = 0; nt < 4; ++nt)
#pragma unroll
          for (int r = 0; r < 4; ++r) pm = fmaxf(pm, s[h][nt][r]);
        float ps = 0.f;
        if (__all(pm <= 11.0f)) {  // defer: no sub, no rescale
#pragma unroll
          for (int nt = 0; nt < 4; ++nt)
#pragma unroll
            for (int r = 0; r < 4; ++r) {
              const float p = exp2f(s[h][nt][r]);
              s[h][nt][r] = p;
              ps += p;
            }
        } else {
          float rm = fmaxf(pm, __shfl_xor(pm, 16));
          rm = fmaxf(rm, __shfl_xor(rm, 32));
          const float rmc = fmaxf(rm, 0.f);
          const float sc = exp2f(-rmc);
          m_[h] += rmc;
          l_[h] *= sc;
#pragma unroll
          for (int nt = 0; nt < 4; ++nt)
#pragma unroll
            for (int r = 0; r < 4; ++r) o[h][nt][r] *= sc;
#pragma unroll
          for (int nt = 0; nt < 4; ++nt)
#pragma unroll
            for (int r = 0; r < 4; ++r) {
              const float p = exp2f(s[h][nt][r] - rmc);
              s[h][nt][r] = p;
              ps += p;
            }
        }
        l_[h] += ps;  // per-lane partial; reduced in epilogue

        // P -> LDS (bf16, 8B packed, XOR-swizzled)
#pragma unroll
        for (int nt = 0; nt < 4; ++nt) {
          bf16x4 pk;
#pragma unroll
          for (int r = 0; r < 4; ++r) pk[r] = (__bf16)s[h][nt][r];
          *(bf16x4*)(P + h * 2048 + l15 * 128 + ((nt * 32 + l4 * 8) ^ xr)) = pk;
        }
      }
      asm volatile("s_waitcnt lgkmcnt(0)" ::: "memory");
      __builtin_amdgcn_sched_barrier(0);

      // O^T += V^T P^T  (V frags shared across halves)
      bf16x8 pf[2][2];
#pragma unroll
      for (int h = 0; h < 2; ++h)
#pragma unroll
        for (int ks = 0; ks < 2; ++ks)
          pf[h][ks] =
              *(const bf16x8*)(P + h * 2048 + l15 * 128 + ((ks * 64 + l4 * 16) ^ xr));
      __builtin_amdgcn_s_setprio(1);
#pragma unroll
      for (int ks = 0; ks < 2; ++ks)
#pragma unroll
        for (int nt = 0; nt < 4; ++nt) {
          const bf16x8 vf =
              *(const bf16x8*)(Vb + (nt * 16 + l15) * 128 + ((ks * 64 + l4 * 16) ^ xr));
          o[0][nt] = __builtin_amdgcn_mfma_f32_16x16x32_bf16(vf, pf[0][ks], o[0][nt], 0, 0, 0);
          o[1][nt] = __builtin_amdgcn_mfma_f32_16x16x32_bf16(vf, pf[1][ks], o[1][nt], 0, 0, 0);
        }
      __builtin_amdgcn_s_setprio(0);
    }

    __builtin_amdgcn_s_barrier();  // all waves done with buf[cur] before re-stage
    asm volatile("" ::: "memory");
    cur ^= 1;
  }

  // epilogue
  const int b = bh >> 4, h16 = bh & 15;
#pragma unroll
  for (int h = 0; h < 2; ++h) {
    float lsum = l_[h] + __shfl_xor(l_[h], 16);
    lsum += __shfl_xor(lsum, 32);
    const float inv = 1.0f / lsum;
    const int q = q0w + h * 16 + l15;
#pragma unroll
    for (int nt = 0; nt < 4; ++nt) {
      bf16x4 yv;
#pragma unroll
      for (int r = 0; r < 4; ++r) yv[r] = (__bf16)(o[h][nt][r] * inv);
      *(bf16x4*)(y + ((size_t)(b * kT + q)) * kC + h16 * kD + nt * 16 + l4 * 4) = yv;
    }
  }
}

extern "C" void kernel_launch(void* const* d_in, const int* in_sizes, int n_in,
                              void* d_out, int out_size, void* d_ws, size_t ws_size,
                              hipStream_t stream) {
  const float* x = (const float*)d_in[0];
  const float* wqkv = (const float*)d_in[1];
  const float* wproj = (const float*)d_in[2];
  const float* pe = (const float*)d_in[3];

  char* ws = (char*)d_ws;
  uint16_t* xp = (uint16_t*)(ws);                          // 8MB, reused as y
  uint16_t* wq = (uint16_t*)(ws + (size_t)(8u << 20));     // 6MB
  uint16_t* wp = (uint16_t*)(ws + (size_t)(14u << 20));    // 2MB
  uint16_t* qbuf = (uint16_t*)(ws + (size_t)(16u << 20));  // 8MB
  uint16_t* kbuf = (uint16_t*)(ws + (size_t)(24u << 20));  // 8MB
  uint16_t* vTb = (uint16_t*)(ws + (size_t)(32u << 20));   // 8MB (total 40MB)

  prep_all<<<dim3(8192), 256, 0, stream>>>(x, pe, wqkv, wproj, xp, wq, wp);

  // qkv = xp @ wqkv^T : M=4096, N=3072 (256x192 tiles, 256 blocks)
  gemm_qkv<<<dim3(256), 512, 0, stream>>>(xp, wq, qbuf, kbuf, vTb);

  // attention -> y (stored into xp buffer, [B,T,C] bf16)
  attn<<<dim3(kB * kH, kT / 128), 256, 0, stream>>>(qbuf, kbuf, vTb, xp);

  // out = y @ wproj^T : M=4096, N=1024, f32 out
  gemm_proj<<<dim3(32, 8), 256, 0, stream>>>(xp, wp, (float*)d_out);
}

// Round 7
// 127.675 us; speedup vs baseline: 1.0227x; 1.0227x over previous
//
#include <hip/hip_runtime.h>
#include <cstdint>

typedef __bf16 bf16x8 __attribute__((ext_vector_type(8)));
typedef __bf16 bf16x4 __attribute__((ext_vector_type(4)));
typedef float  f32x4  __attribute__((ext_vector_type(4)));

static constexpr int kB = 2, kT = 2048, kC = 1024, kH = 16, kD = 64;
static constexpr int kK = 1024;  // GEMM inner dim (= kC)

__device__ __forceinline__ uint16_t f2bf(float f) {
  uint32_t u = __builtin_bit_cast(uint32_t, f);
  u += 0x7FFFu + ((u >> 16) & 1u);
  return (uint16_t)(u >> 16);
}

__device__ __forceinline__ void gl_lds16(const void* g, void* l) {
  __builtin_amdgcn_global_load_lds((__attribute__((address_space(1))) void*)(void*)g,
                                   (__attribute__((address_space(3))) void*)l, 16, 0, 0);
}

// ---------------- fused prep: xp = bf16(x+pe); w casts ----------------
__global__ __launch_bounds__(256) void prep_all(const float* __restrict__ x,
                                                const float* __restrict__ pe,
                                                const float* __restrict__ wqkv,
                                                const float* __restrict__ wproj,
                                                uint16_t* __restrict__ xp,
                                                uint16_t* __restrict__ wq,
                                                uint16_t* __restrict__ wp) {
  constexpr int NX = kB * kT * kC / 4;   // 1048576
  constexpr int NWQ = 3 * kC * kC / 4;   // 786432
  const int i = blockIdx.x * 256 + threadIdx.x;
  if (i < NX) {
    const float4 xv = ((const float4*)x)[i];
    const int c4 = i & (kC / 4 - 1);
    const int t = (i / (kC / 4)) & (kT - 1);
    const float4 pv = ((const float4*)pe)[t * (kC / 4) + c4];
    ushort4 o;
    o.x = f2bf(xv.x + pv.x);
    o.y = f2bf(xv.y + pv.y);
    o.z = f2bf(xv.z + pv.z);
    o.w = f2bf(xv.w + pv.w);
    ((ushort4*)xp)[i] = o;
  } else if (i < NX + NWQ) {
    const int j = i - NX;
    const float4 v = ((const float4*)wqkv)[j];
    ushort4 u;
    u.x = f2bf(v.x); u.y = f2bf(v.y); u.z = f2bf(v.z); u.w = f2bf(v.w);
    ((ushort4*)wq)[j] = u;
  } else {
    const int j = i - NX - NWQ;
    const float4 v = ((const float4*)wproj)[j];
    ushort4 u;
    u.x = f2bf(v.x); u.y = f2bf(v.y); u.z = f2bf(v.z); u.w = f2bf(v.w);
    ((ushort4*)wp)[j] = u;
  }
}

// ---------------- QKV GEMM: 256x256 tile, 8-phase counted-vmcnt (R5 proven) --
__global__ __launch_bounds__(512, 2) void gemm_qkv(const uint16_t* __restrict__ A,
                                                   const uint16_t* __restrict__ W,
                                                   uint16_t* __restrict__ qb,
                                                   uint16_t* __restrict__ kb,
                                                   uint16_t* __restrict__ vT) {
  // LDS: A: buf*32K + half*16K  | B: 64K + buf*32K + half*16K   (128 KiB)
  __shared__ __align__(1024) char lds[131072];
  const int tid = threadIdx.x;
  const int lane = tid & 63;
  const int wid = tid >> 6;
  const int l15 = lane & 15, l4 = lane >> 4;
  const int WM = wid >> 2, WN = wid & 3;
  const int orig = (int)blockIdx.x;
  const int xcd = orig & 7, j = orig >> 3;
  const int m0 = (xcd * 2 + (j & 1)) * 256;
  const int n0 = (j >> 1) * 256;
  constexpr int NKT = kK / 64;  // 16 K-tiles
  constexpr int NIT = NKT / 2;  // 8 iters

  f32x4 acc[4][4][2] = {};  // [quadrant][mt][nt]

  auto stage = [&](int isA, int buf, int half, int kt) {
#pragma unroll
    for (int c = 0; c < 2; ++c) {
      const int off = (c * 512 + tid) * 16;  // 0..16K
      const int lr = off >> 7, cbl = off & 127;
      const size_t grow = (size_t)((isA ? m0 : n0) + half * 128 + lr) * kK + kt * 64;
      gl_lds16((const char*)(isA ? A : W) + grow * 2 + (cbl ^ ((lr & 7) << 4)),
               lds + (isA ? 0 : 65536) + buf * 32768 + half * 16384 + off);
    }
  };
  auto bar = [&] {
    asm volatile("" ::: "memory");
    __builtin_amdgcn_s_barrier();
    asm volatile("" ::: "memory");
  };

  // prologue: A0(0) B0(0) A1(0) B1(0) A0(1) B0(1)
  stage(1, 0, 0, 0); stage(0, 0, 0, 0);
  stage(1, 0, 1, 0); stage(0, 0, 1, 0);
  stage(1, 1, 0, 1); stage(0, 1, 0, 1);

  for (int i = 0; i < NIT; ++i) {
#pragma unroll
    for (int p = 0; p < 8; ++p) {
      constexpr int ISA[8] = {1, 0, 1, 0, 1, 0, 1, 0};
      constexpr int HLF[8] = {1, 1, 0, 0, 1, 1, 0, 0};
      constexpr int TOF[8] = {1, 1, 2, 2, 2, 2, 3, 3};
      const int qr = (p >> 1) & 1, qc = p & 1;
      const int cbuf = (p >> 2) & 1, q4 = p & 3;
      {
        int kt = 2 * i + TOF[p];
        if (kt > NKT - 1) kt = NKT - 1;  // clamp, never skip (vmcnt counts!)
        stage(ISA[p], TOF[p] & 1, HLF[p], kt);
      }
      const char* Ab = lds + cbuf * 32768 + qr * 16384;
      const char* Bb = lds + 65536 + cbuf * 32768 + qc * 16384;
      bf16x8 af[2][4], bfr[2][2];
      auto reads = [&] {
#pragma unroll
        for (int ks = 0; ks < 2; ++ks) {
#pragma unroll
          for (int mt = 0; mt < 4; ++mt) {
            const int lr = WM * 64 + mt * 16 + l15;
            af[ks][mt] = *(const bf16x8*)(Ab + lr * 128 +
                                          ((ks * 64 + l4 * 16) ^ ((lr & 7) << 4)));
          }
#pragma unroll
          for (int nt = 0; nt < 2; ++nt) {
            const int lr = WN * 32 + nt * 16 + l15;
            bfr[ks][nt] = *(const bf16x8*)(Bb + lr * 128 +
                                           ((ks * 64 + l4 * 16) ^ ((lr & 7) << 4)));
          }
        }
      };
      if (p == 0 || p == 4) {
        asm volatile("s_waitcnt vmcnt(6)" ::: "memory");
        bar();
        reads();
      } else {
        reads();
        bar();
      }
      __builtin_amdgcn_s_setprio(1);
#pragma unroll
      for (int ks = 0; ks < 2; ++ks)
#pragma unroll
        for (int mt = 0; mt < 4; ++mt)
#pragma unroll
          for (int nt = 0; nt < 2; ++nt)
            acc[q4][mt][nt] = __builtin_amdgcn_mfma_f32_16x16x32_bf16(
                af[ks][mt], bfr[ks][nt], acc[q4][mt][nt], 0, 0, 0);
      __builtin_amdgcn_s_setprio(0);
      bar();
    }
  }
  asm volatile("s_waitcnt vmcnt(0)" ::: "memory");
  bar();

  // ---- epilogue ----
  const int sec = n0 >> 10;  // 0:q 1:k 2:v (256-tiles are section-pure)
  const int b = m0 >> 11, tb = m0 & (kT - 1);
  if (sec < 2) {
    uint16_t* dst = (sec == 0) ? qb : kb;
#pragma unroll
    for (int q4 = 0; q4 < 4; ++q4) {
      const int qr = q4 >> 1, qc = q4 & 1;
#pragma unroll
      for (int mt = 0; mt < 4; ++mt)
#pragma unroll
        for (int nt = 0; nt < 2; ++nt)
#pragma unroll
          for (int r = 0; r < 4; ++r) {
            const int m = qr * 128 + WM * 64 + mt * 16 + l4 * 4 + r;
            const int nn = (n0 & (kC - 1)) + qc * 128 + WN * 32 + nt * 16 + l15;
            const int h = nn >> 6, d = nn & 63;
            dst[((size_t)((b * kH + h) * kT + tb + m)) * kD + d] =
                f2bf(acc[q4][mt][nt][r]);
          }
    }
  } else {
    // v: bounce through LDS d-major [n][m] (free transpose), packed 8B writes
#pragma unroll
    for (int q4 = 0; q4 < 4; ++q4) {
      const int qr = q4 >> 1, qc = q4 & 1;
#pragma unroll
      for (int mt = 0; mt < 4; ++mt)
#pragma unroll
        for (int nt = 0; nt < 2; ++nt) {
          const int nl = qc * 128 + WN * 32 + nt * 16 + l15;
          const int mb2 = (qr * 128 + WM * 64 + mt * 16 + l4 * 4) * 2;
          ushort4 pk;
          pk.x = f2bf(acc[q4][mt][nt][0]);
          pk.y = f2bf(acc[q4][mt][nt][1]);
          pk.z = f2bf(acc[q4][mt][nt][2]);
          pk.w = f2bf(acc[q4][mt][nt][3]);
          *(ushort4*)(lds + nl * 512 + (mb2 ^ ((nl & 7) << 4))) = pk;
        }
    }
    bar();
#pragma unroll
    for (int it = 0; it < 16; ++it) {
      const int chunk = it * 512 + tid;
      const int nr = chunk >> 5, mb = (chunk & 31) * 16;
      const bf16x8 v = *(const bf16x8*)(lds + nr * 512 + (mb ^ ((nr & 7) << 4)));
      const int nn = (n0 - 2048) + nr;
      const int h = nn >> 6, d = nn & 63;
      *(bf16x8*)(vT + ((size_t)((b * kH + h) * kD + d)) * kT + tb + (chunk & 31) * 8) = v;
    }
  }
}

// ---------------- proj GEMM: C = A[M,K] * W[N,K]^T, f32 out (128^2) ----------
__global__ __launch_bounds__(256) void gemm_proj(const uint16_t* __restrict__ A,
                                                 const uint16_t* __restrict__ W,
                                                 float* __restrict__ out) {
  __shared__ __align__(1024) char lds[32768];
  const int lane = threadIdx.x & 63;
  const int wid = threadIdx.x >> 6;
  const int l15 = lane & 15, l4 = lane >> 4;
  const int wm = wid >> 1, wn = wid & 1;
  const int orig = (int)(blockIdx.y * gridDim.x + blockIdx.x);
  const int xcd = orig & 7, j = orig >> 3;
  const int m0 = (xcd * 4 + (j & 3)) * 128;
  const int n0 = (j >> 2) * 128;

  f32x4 acc[4][4] = {};

  for (int k0 = 0; k0 < kK; k0 += 64) {
#pragma unroll
    for (int jj = 0; jj < 4; ++jj) {
      const int off = wid * 4096 + jj * 1024 + lane * 16;
      const int row = off >> 7;
      const int colb = (off & 127) ^ ((row & 7) << 4);
      gl_lds16((const char*)A + ((size_t)(m0 + row) * kK + k0) * 2 + colb,
               lds + wid * 4096 + jj * 1024);
      gl_lds16((const char*)W + ((size_t)(n0 + row) * kK + k0) * 2 + colb,
               lds + 16384 + wid * 4096 + jj * 1024);
    }
    __syncthreads();
#pragma unroll
    for (int ks = 0; ks < 2; ++ks) {
      bf16x8 af[4], bf_[4];
#pragma unroll
      for (int mt = 0; mt < 4; ++mt) {
        const int r = wm * 64 + mt * 16 + l15;
        const int cb = (l4 * 16 + ks * 64) ^ ((r & 7) << 4);
        af[mt] = *(const bf16x8*)(lds + r * 128 + cb);
      }
#pragma unroll
      for (int nt = 0; nt < 4; ++nt) {
        const int r = wn * 64 + nt * 16 + l15;
        const int cb = (l4 * 16 + ks * 64) ^ ((r & 7) << 4);
        bf_[nt] = *(const bf16x8*)(lds + 16384 + r * 128 + cb);
      }
#pragma unroll
      for (int mt = 0; mt < 4; ++mt)
#pragma unroll
        for (int nt = 0; nt < 4; ++nt)
          acc[mt][nt] = __builtin_amdgcn_mfma_f32_16x16x32_bf16(af[mt], bf_[nt],
                                                                acc[mt][nt], 0, 0, 0);
    }
    __syncthreads();
  }

#pragma unroll
  for (int mt = 0; mt < 4; ++mt)
#pragma unroll
    for (int nt = 0; nt < 4; ++nt)
#pragma unroll
      for (int r = 0; r < 4; ++r) {
        const int m = m0 + wm * 64 + mt * 16 + l4 * 4 + r;
        const int n = n0 + wn * 64 + nt * 16 + l15;
        out[(size_t)m * kC + n] = acc[mt][nt][r];
      }
}

// ---------------- flash attention: 2 waves x 32 q-rows, 64-row blocks --------
// Same 1024-block LPT balance as R5; K/V LDS frags read once per tile and
// shared across each wave's two 16-row halves (halves LDS traffic per MFMA).
// Shifted-domain exp2 softmax with defer-max. Full grid co-resident
// (4 blocks/CU x 2 waves). XCD ~ bh%8 clusters each head's K/V in L2.
__global__ __launch_bounds__(128, 2) void attn(const uint16_t* __restrict__ qb,
                                               const uint16_t* __restrict__ kb,
                                               const uint16_t* __restrict__ vT,
                                               uint16_t* __restrict__ y) {
  // LDS: K[2] @ 0/8192 | V[2] @ 16384/24576 | P @ 32768 + wid*4096 (40 KiB)
  __shared__ __align__(1024) char lds[40960];
  const int lane = threadIdx.x & 63;
  const int wid = threadIdx.x >> 6;  // 0..1
  const int l15 = lane & 15, l4 = lane >> 4;
  const int bh = blockIdx.x;
  const int qt = (int)(gridDim.y - 1) - (int)blockIdx.y;
  const int q0w = qt * 64 + wid * 32;  // this wave's first q row
  const size_t base = (size_t)bh * kT * kD;
  const uint16_t* Q = qb + base;
  const uint16_t* Kp = kb + base;
  const uint16_t* Vt = vT + base;
  char* P = lds + 32768 + wid * 4096;
  const int xr = (l15 & 7) << 4;

  // Q fragments, scaled by log2(e)/sqrt(d) (exp2-domain softmax)
  bf16x8 qf[2][2];
#pragma unroll
  for (int h = 0; h < 2; ++h)
#pragma unroll
    for (int ks = 0; ks < 2; ++ks) {
      bf16x8 t =
          *(const bf16x8*)(Q + (size_t)(q0w + h * 16 + l15) * kD + ks * 32 + l4 * 8);
#pragma unroll
      for (int i = 0; i < 8; ++i) t[i] = (__bf16)((float)t[i] * 0.1803368801f);
      qf[h][ks] = t;
    }

  float m_[2] = {0.f, 0.f}, l_[2] = {0.f, 0.f};  // shifted-domain; m_ row-uniform
  f32x4 o[2][4] = {};  // O^T[d = nt*16 + l4*4 + r][q = l15] per half

  const int nkt = qt + 1;  // block-uniform

  // cooperative stage of one K/V tile (8 gl_lds per wave; 2 waves -> 16 KB)
  auto STAGE = [&](int bi, int k0) {
#pragma unroll
    for (int c = 0; c < 4; ++c) {
      const int call = wid * 4 + c;
      const int row = call * 8 + (lane >> 3);
      const int colb = (((lane & 7) ^ ((lane >> 3) & 7)) << 4);
      gl_lds16((const char*)Kp + ((size_t)(k0 + row) * kD) * 2 + colb,
               lds + bi * 8192 + call * 1024);
      gl_lds16((const char*)Vt + ((size_t)row * kT + k0) * 2 + colb,
               lds + 16384 + bi * 8192 + call * 1024);
    }
  };

  int cur = 0;
  STAGE(0, 0);
  for (int kt = 0; kt < nkt; ++kt) {
    const int k0 = kt * 64;
    const bool hasnext = (kt + 1 < nkt);
    if (hasnext) STAGE(cur ^ 1, k0 + 64);
    if (hasnext)
      asm volatile("s_waitcnt vmcnt(8)" ::: "memory");
    else
      asm volatile("s_waitcnt vmcnt(0)" ::: "memory");
    __builtin_amdgcn_s_barrier();
    asm volatile("" ::: "memory");

    const char* Kb = lds + cur * 8192;
    const char* Vb = lds + 16384 + cur * 8192;

    // S' = K Q^T - m (shifted log2-domain; C-init = -m); K frags shared by halves
    f32x4 s[2][4];
#pragma unroll
    for (int h = 0; h < 2; ++h)
#pragma unroll
      for (int nt = 0; nt < 4; ++nt)
        s[h][nt] = (f32x4){-m_[h], -m_[h], -m_[h], -m_[h]};
    __builtin_amdgcn_s_setprio(1);
#pragma unroll
    for (int ks = 0; ks < 2; ++ks)
#pragma unroll
      for (int nt = 0; nt < 4; ++nt) {
        const bf16x8 kf =
            *(const bf16x8*)(Kb + (nt * 16 + l15) * 128 + ((ks * 64 + l4 * 16) ^ xr));
        s[0][nt] = __builtin_amdgcn_mfma_f32_16x16x32_bf16(kf, qf[0][ks], s[0][nt], 0, 0, 0);
        s[1][nt] = __builtin_amdgcn_mfma_f32_16x16x32_bf16(kf, qf[1][ks], s[1][nt], 0, 0, 0);
      }
    __builtin_amdgcn_s_setprio(0);

    // causal mask + softmax per half
#pragma unroll
    for (int h = 0; h < 2; ++h) {
      if (k0 + 63 > q0w + h * 16) {  // diagonal tile only
        const int qq = q0w + h * 16 + l15;
#pragma unroll
        for (int nt = 0; nt < 4; ++nt)
#pragma unroll
          for (int r = 0; r < 4; ++r)
            if (k0 + nt * 16 + l4 * 4 + r > qq) s[h][nt][r] = -1e30f;
      }
      float pm = s[h][0][0];
#pragma unroll
      for (int nt = 0; nt < 4; ++nt)
#pragma unroll
        for (int r = 0; r < 4; ++r) pm = fmaxf(pm, s[h][nt][r]);
      float ps = 0.f;
      if (__all(pm <= 11.0f)) {  // defer: no sub, no rescale
#pragma unroll
        for (int nt = 0; nt < 4; ++nt)
#pragma unroll
          for (int r = 0; r < 4; ++r) {
            const float p = exp2f(s[h][nt][r]);
            s[h][nt][r] = p;
            ps += p;
          }
      } else {
        float rm = fmaxf(pm, __shfl_xor(pm, 16));
        rm = fmaxf(rm, __shfl_xor(rm, 32));
        const float rmc = fmaxf(rm, 0.f);
        const float sc = exp2f(-rmc);
        m_[h] += rmc;
        l_[h] *= sc;
#pragma unroll
        for (int nt = 0; nt < 4; ++nt)
#pragma unroll
          for (int r = 0; r < 4; ++r) o[h][nt][r] *= sc;
#pragma unroll
        for (int nt = 0; nt < 4; ++nt)
#pragma unroll
          for (int r = 0; r < 4; ++r) {
            const float p = exp2f(s[h][nt][r] - rmc);
            s[h][nt][r] = p;
            ps += p;
          }
      }
      l_[h] += ps;  // per-lane partial; reduced in epilogue

      // P -> LDS (bf16, 8B packed, XOR-swizzled)
#pragma unroll
      for (int nt = 0; nt < 4; ++nt) {
        bf16x4 pk;
#pragma unroll
        for (int r = 0; r < 4; ++r) pk[r] = (__bf16)s[h][nt][r];
        *(bf16x4*)(P + h * 2048 + l15 * 128 + ((nt * 32 + l4 * 8) ^ xr)) = pk;
      }
    }
    asm volatile("s_waitcnt lgkmcnt(0)" ::: "memory");
    __builtin_amdgcn_sched_barrier(0);

    // O^T += V^T P^T  (V frags shared across halves)
    bf16x8 pf[2][2];
#pragma unroll
    for (int h = 0; h < 2; ++h)
#pragma unroll
      for (int ks = 0; ks < 2; ++ks)
        pf[h][ks] =
            *(const bf16x8*)(P + h * 2048 + l15 * 128 + ((ks * 64 + l4 * 16) ^ xr));
    __builtin_amdgcn_s_setprio(1);
#pragma unroll
    for (int ks = 0; ks < 2; ++ks)
#pragma unroll
      for (int nt = 0; nt < 4; ++nt) {
        const bf16x8 vf =
            *(const bf16x8*)(Vb + (nt * 16 + l15) * 128 + ((ks * 64 + l4 * 16) ^ xr));
        o[0][nt] = __builtin_amdgcn_mfma_f32_16x16x32_bf16(vf, pf[0][ks], o[0][nt], 0, 0, 0);
        o[1][nt] = __builtin_amdgcn_mfma_f32_16x16x32_bf16(vf, pf[1][ks], o[1][nt], 0, 0, 0);
      }
    __builtin_amdgcn_s_setprio(0);

    __builtin_amdgcn_s_barrier();  // both waves done with buf[cur] before re-stage
    asm volatile("" ::: "memory");
    cur ^= 1;
  }

  // epilogue
  const int b = bh >> 4, h16 = bh & 15;
#pragma unroll
  for (int h = 0; h < 2; ++h) {
    float lsum = l_[h] + __shfl_xor(l_[h], 16);
    lsum += __shfl_xor(lsum, 32);
    const float inv = 1.0f / lsum;
    const int q = q0w + h * 16 + l15;
#pragma unroll
    for (int nt = 0; nt < 4; ++nt) {
      bf16x4 yv;
#pragma unroll
      for (int r = 0; r < 4; ++r) yv[r] = (__bf16)(o[h][nt][r] * inv);
      *(bf16x4*)(y + ((size_t)(b * kT + q)) * kC + h16 * kD + nt * 16 + l4 * 4) = yv;
    }
  }
}

extern "C" void kernel_launch(void* const* d_in, const int* in_sizes, int n_in,
                              void* d_out, int out_size, void* d_ws, size_t ws_size,
                              hipStream_t stream) {
  const float* x = (const float*)d_in[0];
  const float* wqkv = (const float*)d_in[1];
  const float* wproj = (const float*)d_in[2];
  const float* pe = (const float*)d_in[3];

  char* ws = (char*)d_ws;
  uint16_t* xp = (uint16_t*)(ws);                          // 8MB, reused as y
  uint16_t* wq = (uint16_t*)(ws + (size_t)(8u << 20));     // 6MB
  uint16_t* wp = (uint16_t*)(ws + (size_t)(14u << 20));    // 2MB
  uint16_t* qbuf = (uint16_t*)(ws + (size_t)(16u << 20));  // 8MB
  uint16_t* kbuf = (uint16_t*)(ws + (size_t)(24u << 20));  // 8MB
  uint16_t* vTb = (uint16_t*)(ws + (size_t)(32u << 20));   // 8MB (total 40MB)

  prep_all<<<dim3(8192), 256, 0, stream>>>(x, pe, wqkv, wproj, xp, wq, wp);

  // qkv = xp @ wqkv^T : M=4096, N=3072 (256^2 tiles, 192 blocks)
  gemm_qkv<<<dim3(192), 512, 0, stream>>>(xp, wq, qbuf, kbuf, vTb);

  // attention -> y (stored into xp buffer, [B,T,C] bf16)
  attn<<<dim3(kB * kH, kT / 64), 128, 0, stream>>>(qbuf, kbuf, vTb, xp);

  // out = y @ wproj^T : M=4096, N=1024, f32 out
  gemm_proj<<<dim3(32, 8), 256, 0, stream>>>(xp, wp, (float*)d_out);
}

// Round 8
// 107.732 us; speedup vs baseline: 1.2120x; 1.1851x over previous
//
#include <hip/hip_runtime.h>
#include <cstdint>

typedef __bf16 bf16x8 __attribute__((ext_vector_type(8)));
typedef __bf16 bf16x4 __attribute__((ext_vector_type(4)));
typedef float  f32x4  __attribute__((ext_vector_type(4)));

static constexpr int kB = 2, kT = 2048, kC = 1024, kH = 16, kD = 64;
static constexpr int kK = 1024;  // GEMM inner dim (= kC)

__device__ __forceinline__ uint16_t f2bf(float f) {
  uint32_t u = __builtin_bit_cast(uint32_t, f);
  u += 0x7FFFu + ((u >> 16) & 1u);
  return (uint16_t)(u >> 16);
}

__device__ __forceinline__ void gl_lds16(const void* g, void* l) {
  __builtin_amdgcn_global_load_lds((__attribute__((address_space(1))) void*)(void*)g,
                                   (__attribute__((address_space(3))) void*)l, 16, 0, 0);
}

// ---------------- fused prep: xp = bf16(x+pe); w casts ----------------
__global__ __launch_bounds__(256) void prep_all(const float* __restrict__ x,
                                                const float* __restrict__ pe,
                                                const float* __restrict__ wqkv,
                                                const float* __restrict__ wproj,
                                                uint16_t* __restrict__ xp,
                                                uint16_t* __restrict__ wq,
                                                uint16_t* __restrict__ wp) {
  constexpr int NX = kB * kT * kC / 4;   // 1048576
  constexpr int NWQ = 3 * kC * kC / 4;   // 786432
  const int i = blockIdx.x * 256 + threadIdx.x;
  if (i < NX) {
    const float4 xv = ((const float4*)x)[i];
    const int c4 = i & (kC / 4 - 1);
    const int t = (i / (kC / 4)) & (kT - 1);
    const float4 pv = ((const float4*)pe)[t * (kC / 4) + c4];
    ushort4 o;
    o.x = f2bf(xv.x + pv.x);
    o.y = f2bf(xv.y + pv.y);
    o.z = f2bf(xv.z + pv.z);
    o.w = f2bf(xv.w + pv.w);
    ((ushort4*)xp)[i] = o;
  } else if (i < NX + NWQ) {
    const int j = i - NX;
    const float4 v = ((const float4*)wqkv)[j];
    ushort4 u;
    u.x = f2bf(v.x); u.y = f2bf(v.y); u.z = f2bf(v.z); u.w = f2bf(v.w);
    ((ushort4*)wq)[j] = u;
  } else {
    const int j = i - NX - NWQ;
    const float4 v = ((const float4*)wproj)[j];
    ushort4 u;
    u.x = f2bf(v.x); u.y = f2bf(v.y); u.z = f2bf(v.z); u.w = f2bf(v.w);
    ((ushort4*)wp)[j] = u;
  }
}

// ---------------- QKV GEMM: 256x256 tile, 4-phase (128row x 256col) ----------
// M=4096 N=3072 K=1024. 8 waves (2M x 4N); per phase wave computes 64x64
// (32 MFMA) from 8 A-frag reads; B-frags (8) read once per buffer at the h0
// phase and reused at h1 (regs persist across barriers) -> 0.375 reads/MFMA.
// Iter = k-tiles {2i (buf0), 2i+1 (buf1)}. Stages (4 gl_lds/thread each):
// p0: A-buf1<-kt2i+1, p1: B-buf1<-kt2i+1, p2: A-buf0<-kt2i+2, p3: B-buf0.
// vmcnt(4) at p0/p2 (buffer-first), vmcnt(8) at p1/p3. LDS 128 KiB.
__global__ __launch_bounds__(512, 2) void gemm_qkv(const uint16_t* __restrict__ A,
                                                   const uint16_t* __restrict__ W,
                                                   uint16_t* __restrict__ qb,
                                                   uint16_t* __restrict__ kb,
                                                   uint16_t* __restrict__ vT) {
  __shared__ __align__(1024) char lds[131072];  // A: 2x32K @0 | B: 2x32K @65536
  const int tid = threadIdx.x;
  const int lane = tid & 63;
  const int wid = tid >> 6;
  const int l15 = lane & 15, l4 = lane >> 4;
  const int WM = wid >> 2, WN = wid & 3;  // 2 x 4
  const int orig = (int)blockIdx.x;
  const int xcd = orig & 7, j = orig >> 3;
  const int m0 = (xcd * 2 + (j & 1)) * 256;  // 16 m-tiles
  const int n0 = (j >> 1) * 256;             // 12 n-tiles

  f32x4 acc[2][4][4] = {};  // [row-half][mt][nt]
  bf16x8 bfp[2][4];         // B frags, persist h0->h1

  auto stage = [&](int isA, int buf, int kt) {
#pragma unroll
    for (int c = 0; c < 4; ++c) {
      const int off = (c * 512 + tid) * 16;  // 0..32K
      const int lr = off >> 7, cbl = off & 127;
      const size_t grow = (size_t)((isA ? m0 : n0) + lr) * kK + kt * 64;
      gl_lds16((const char*)(isA ? A : W) + grow * 2 + (cbl ^ ((lr & 7) << 4)),
               lds + (isA ? 0 : 65536) + buf * 32768 + off);
    }
  };

#define QKV_PHASE(CBUF, H, SA, SBUF, KT, VM)                                      \
  {                                                                               \
    stage(SA, SBUF, KT);                                                          \
    if (VM == 4)                                                                  \
      asm volatile("s_waitcnt vmcnt(4)" ::: "memory");                            \
    else                                                                          \
      asm volatile("s_waitcnt vmcnt(8)" ::: "memory");                            \
    __builtin_amdgcn_s_barrier();                                                 \
    asm volatile("" ::: "memory");                                                \
    const char* Ab = lds + (CBUF)*32768;                                          \
    const char* Bb = lds + 65536 + (CBUF)*32768;                                  \
    if ((H) == 0) {                                                               \
      _Pragma("unroll") for (int ks = 0; ks < 2; ++ks)                            \
          _Pragma("unroll") for (int nt = 0; nt < 4; ++nt) {                      \
        const int lr = WN * 64 + nt * 16 + l15;                                   \
        bfp[ks][nt] = *(const bf16x8*)(Bb + lr * 128 +                            \
                                       ((ks * 64 + l4 * 16) ^ ((lr & 7) << 4)));  \
      }                                                                           \
    }                                                                             \
    _Pragma("unroll") for (int ks = 0; ks < 2; ++ks) {                            \
      bf16x8 af[4];                                                               \
      _Pragma("unroll") for (int mt = 0; mt < 4; ++mt) {                          \
        const int lr = (H)*128 + WM * 64 + mt * 16 + l15;                         \
        af[mt] = *(const bf16x8*)(Ab + lr * 128 +                                 \
                                  ((ks * 64 + l4 * 16) ^ ((lr & 7) << 4)));       \
      }                                                                           \
      __builtin_amdgcn_s_setprio(1);                                              \
      _Pragma("unroll") for (int mt = 0; mt < 4; ++mt)                            \
          _Pragma("unroll") for (int nt = 0; nt < 4; ++nt)                        \
              acc[H][mt][nt] = __builtin_amdgcn_mfma_f32_16x16x32_bf16(           \
                  af[mt], bfp[ks][nt], acc[H][mt][nt], 0, 0, 0);                  \
      __builtin_amdgcn_s_setprio(0);                                              \
    }                                                                             \
    asm volatile("" ::: "memory");                                                \
    __builtin_amdgcn_s_barrier();                                                 \
    asm volatile("" ::: "memory");                                                \
  }

  // prologue: buf0 <- kt0 (A then B) = 8 outstanding
  stage(1, 0, 0);
  stage(0, 0, 0);

  for (int i = 0; i < 8; ++i) {
    const int ktb1 = 2 * i + 1;
    const int ktb0 = (2 * i + 2 > 15) ? 15 : 2 * i + 2;  // clamp, never skip
    QKV_PHASE(0, 0, 1, 1, ktb1, 4);  // read buf0 h0; stage A-buf1
    QKV_PHASE(0, 1, 0, 1, ktb1, 8);  // read buf0 h1; stage B-buf1
    QKV_PHASE(1, 0, 1, 0, ktb0, 4);  // read buf1 h0; stage A-buf0
    QKV_PHASE(1, 1, 0, 0, ktb0, 8);  // read buf1 h1; stage B-buf0
  }
  asm volatile("s_waitcnt vmcnt(0)" ::: "memory");
  __builtin_amdgcn_s_barrier();
  asm volatile("" ::: "memory");

  // ---- epilogue (sec-pure 256-tiles): q/k direct, v via LDS transpose ----
  const int sec = n0 >> 10;
  const int b = m0 >> 11, tb = m0 & (kT - 1);
  if (sec < 2) {
    uint16_t* dst = (sec == 0) ? qb : kb;
#pragma unroll
    for (int h = 0; h < 2; ++h)
#pragma unroll
      for (int mt = 0; mt < 4; ++mt)
#pragma unroll
        for (int nt = 0; nt < 4; ++nt)
#pragma unroll
          for (int r = 0; r < 4; ++r) {
            const int m = h * 128 + WM * 64 + mt * 16 + l4 * 4 + r;
            const int nn = (n0 & (kC - 1)) + WN * 64 + nt * 16 + l15;
            const int hh = nn >> 6, d = nn & 63;
            dst[((size_t)((b * kH + hh) * kT + tb + m)) * kD + d] =
                f2bf(acc[h][mt][nt][r]);
          }
  } else {
    // v: bounce through LDS d-major [n][m] (free transpose), packed stores
#pragma unroll
    for (int h = 0; h < 2; ++h)
#pragma unroll
      for (int mt = 0; mt < 4; ++mt)
#pragma unroll
        for (int nt = 0; nt < 4; ++nt) {
          const int nl = WN * 64 + nt * 16 + l15;
          const int mb2 = (h * 128 + WM * 64 + mt * 16 + l4 * 4) * 2;
          ushort4 pk;
          pk.x = f2bf(acc[h][mt][nt][0]);
          pk.y = f2bf(acc[h][mt][nt][1]);
          pk.z = f2bf(acc[h][mt][nt][2]);
          pk.w = f2bf(acc[h][mt][nt][3]);
          *(ushort4*)(lds + nl * 512 + (mb2 ^ ((nl & 7) << 4))) = pk;
        }
    asm volatile("" ::: "memory");
    __builtin_amdgcn_s_barrier();
    asm volatile("" ::: "memory");
#pragma unroll
    for (int it = 0; it < 16; ++it) {
      const int chunk = it * 512 + tid;
      const int nr = chunk >> 5, mb = (chunk & 31) * 16;
      const bf16x8 v = *(const bf16x8*)(lds + nr * 512 + (mb ^ ((nr & 7) << 4)));
      const int nn = (n0 - 2048) + nr;
      const int hh = nn >> 6, d = nn & 63;
      *(bf16x8*)(vT + ((size_t)((b * kH + hh) * kD + d)) * kT + tb + (chunk & 31) * 8) = v;
    }
  }
#undef QKV_PHASE
}

// ---------------- proj GEMM: C = A[M,K] * W[N,K]^T, f32 out (128^2) ----------
__global__ __launch_bounds__(256) void gemm_proj(const uint16_t* __restrict__ A,
                                                 const uint16_t* __restrict__ W,
                                                 float* __restrict__ out) {
  __shared__ __align__(1024) char lds[32768];
  const int lane = threadIdx.x & 63;
  const int wid = threadIdx.x >> 6;
  const int l15 = lane & 15, l4 = lane >> 4;
  const int wm = wid >> 1, wn = wid & 1;
  const int orig = (int)(blockIdx.y * gridDim.x + blockIdx.x);
  const int xcd = orig & 7, j = orig >> 3;
  const int m0 = (xcd * 4 + (j & 3)) * 128;
  const int n0 = (j >> 2) * 128;

  f32x4 acc[4][4] = {};

  for (int k0 = 0; k0 < kK; k0 += 64) {
#pragma unroll
    for (int jj = 0; jj < 4; ++jj) {
      const int off = wid * 4096 + jj * 1024 + lane * 16;
      const int row = off >> 7;
      const int colb = (off & 127) ^ ((row & 7) << 4);
      gl_lds16((const char*)A + ((size_t)(m0 + row) * kK + k0) * 2 + colb,
               lds + wid * 4096 + jj * 1024);
      gl_lds16((const char*)W + ((size_t)(n0 + row) * kK + k0) * 2 + colb,
               lds + 16384 + wid * 4096 + jj * 1024);
    }
    __syncthreads();
#pragma unroll
    for (int ks = 0; ks < 2; ++ks) {
      bf16x8 af[4], bf_[4];
#pragma unroll
      for (int mt = 0; mt < 4; ++mt) {
        const int r = wm * 64 + mt * 16 + l15;
        const int cb = (l4 * 16 + ks * 64) ^ ((r & 7) << 4);
        af[mt] = *(const bf16x8*)(lds + r * 128 + cb);
      }
#pragma unroll
      for (int nt = 0; nt < 4; ++nt) {
        const int r = wn * 64 + nt * 16 + l15;
        const int cb = (l4 * 16 + ks * 64) ^ ((r & 7) << 4);
        bf_[nt] = *(const bf16x8*)(lds + 16384 + r * 128 + cb);
      }
#pragma unroll
      for (int mt = 0; mt < 4; ++mt)
#pragma unroll
        for (int nt = 0; nt < 4; ++nt)
          acc[mt][nt] = __builtin_amdgcn_mfma_f32_16x16x32_bf16(af[mt], bf_[nt],
                                                                acc[mt][nt], 0, 0, 0);
    }
    __syncthreads();
  }

#pragma unroll
  for (int mt = 0; mt < 4; ++mt)
#pragma unroll
    for (int nt = 0; nt < 4; ++nt)
#pragma unroll
      for (int r = 0; r < 4; ++r) {
        const int m = m0 + wm * 64 + mt * 16 + l4 * 4 + r;
        const int n = n0 + wn * 64 + nt * 16 + l15;
        out[(size_t)m * kC + n] = acc[mt][nt][r];
      }
}

// ---------------- flash attention (causal), swapped-QK (R5 proven) ----------
__global__ __launch_bounds__(256, 4) void attn(const uint16_t* __restrict__ qb,
                                               const uint16_t* __restrict__ kb,
                                               const uint16_t* __restrict__ vT,
                                               uint16_t* __restrict__ y) {
  // LDS: K[2] @ 0/8192 | V[2] @ 16384/24576 | P @ 32768 + wid*2048
  __shared__ __align__(1024) char lds[40960];
  const int lane = threadIdx.x & 63;
  const int wid = threadIdx.x >> 6;
  const int l15 = lane & 15, l4 = lane >> 4;
  const int bh = blockIdx.x;
  const int qt = (int)(gridDim.y - 1) - (int)blockIdx.y;
  const int q0 = qt * 64 + wid * 16;  // this wave's first q row
  const size_t base = (size_t)bh * kT * kD;
  const uint16_t* Q = qb + base;
  const uint16_t* Kp = kb + base;
  const uint16_t* Vt = vT + base;
  char* P = lds + 32768 + wid * 2048;
  const int xr = (l15 & 7) << 4;

  // Q fragments, scaled by log2(e)/sqrt(d) (exp2-domain softmax)
  bf16x8 qf[2];
#pragma unroll
  for (int ks = 0; ks < 2; ++ks) {
    bf16x8 t = *(const bf16x8*)(Q + (size_t)(q0 + l15) * kD + ks * 32 + l4 * 8);
#pragma unroll
    for (int i = 0; i < 8; ++i) t[i] = (__bf16)((float)t[i] * 0.1803368801f);
    qf[ks] = t;
  }

  float m_ = -1e30f, l_ = 0.f;   // per-lane; m_ kept row-uniform, l_ partial
  f32x4 o[4];                    // O^T[d = nt*16 + l4*4 + r][q = l15]
#pragma unroll
  for (int nt = 0; nt < 4; ++nt) o[nt] = (f32x4){0.f, 0.f, 0.f, 0.f};

  const int nkt = qt + 1;  // wave-uniform

  auto STAGE = [&](int bi, int k0) {
#pragma unroll
    for (int c = 0; c < 2; ++c) {
      const int call = wid * 2 + c;
      const int row = call * 8 + (lane >> 3);
      const int colb = (((lane & 7) ^ ((lane >> 3) & 7)) << 4);
      gl_lds16((const char*)Kp + ((size_t)(k0 + row) * kD) * 2 + colb,
               lds + bi * 8192 + call * 1024);
      gl_lds16((const char*)Vt + ((size_t)row * kT + k0) * 2 + colb,
               lds + 16384 + bi * 8192 + call * 1024);
    }
  };

  int cur = 0;
  STAGE(0, 0);
  for (int kt = 0; kt < nkt; ++kt) {
    const int k0 = kt * 64;
    const bool hasnext = (kt + 1 < nkt);
    if (hasnext) STAGE(cur ^ 1, k0 + 64);
    if (hasnext)
      asm volatile("s_waitcnt vmcnt(4)" ::: "memory");
    else
      asm volatile("s_waitcnt vmcnt(0)" ::: "memory");
    __builtin_amdgcn_s_barrier();
    asm volatile("" ::: "memory");

    const char* Kb = lds + cur * 8192;
    const char* Vb = lds + 16384 + cur * 8192;

    // S^T = K Q^T (log2-domain)
    f32x4 s[4] = {};
    __builtin_amdgcn_s_setprio(1);
#pragma unroll
    for (int ks = 0; ks < 2; ++ks)
#pragma unroll
      for (int nt = 0; nt < 4; ++nt) {
        const bf16x8 kf =
            *(const bf16x8*)(Kb + (nt * 16 + l15) * 128 + ((ks * 64 + l4 * 16) ^ xr));
        s[nt] = __builtin_amdgcn_mfma_f32_16x16x32_bf16(kf, qf[ks], s[nt], 0, 0, 0);
      }
    __builtin_amdgcn_s_setprio(0);

    if (kt == nkt - 1) {  // causal mask on diagonal tile
      const int qq = q0 + l15;
#pragma unroll
      for (int nt = 0; nt < 4; ++nt)
#pragma unroll
        for (int r = 0; r < 4; ++r)
          if (k0 + nt * 16 + l4 * 4 + r > qq) s[nt][r] = -1e30f;
    }

    // online softmax, defer-max
    float pm = s[0][0];
#pragma unroll
    for (int nt = 0; nt < 4; ++nt)
#pragma unroll
      for (int r = 0; r < 4; ++r) pm = fmaxf(pm, s[nt][r]);
    if (!__all(pm <= m_ + 11.0f)) {
      float rm = fmaxf(pm, __shfl_xor(pm, 16));
      rm = fmaxf(rm, __shfl_xor(rm, 32));
      const float newm = fmaxf(m_, rm);
      const float sc = exp2f(m_ - newm);
      m_ = newm;
      l_ *= sc;
#pragma unroll
      for (int nt = 0; nt < 4; ++nt)
#pragma unroll
        for (int r = 0; r < 4; ++r) o[nt][r] *= sc;
    }
    float ps = 0.f;
#pragma unroll
    for (int nt = 0; nt < 4; ++nt)
#pragma unroll
      for (int r = 0; r < 4; ++r) {
        const float p = exp2f(s[nt][r] - m_);
        s[nt][r] = p;
        ps += p;
      }
    l_ += ps;

    // P -> LDS (bf16, 8B packed, XOR-swizzled)
#pragma unroll
    for (int nt = 0; nt < 4; ++nt) {
      bf16x4 pk;
#pragma unroll
      for (int r = 0; r < 4; ++r) pk[r] = (__bf16)s[nt][r];
      *(bf16x4*)(P + l15 * 128 + ((nt * 32 + l4 * 8) ^ xr)) = pk;
    }
    asm volatile("s_waitcnt lgkmcnt(0)" ::: "memory");
    __builtin_amdgcn_sched_barrier(0);

    // O^T += V^T P^T
    bf16x8 pf[2];
#pragma unroll
    for (int ks = 0; ks < 2; ++ks)
      pf[ks] = *(const bf16x8*)(P + l15 * 128 + ((ks * 64 + l4 * 16) ^ xr));
    __builtin_amdgcn_s_setprio(1);
#pragma unroll
    for (int ks = 0; ks < 2; ++ks)
#pragma unroll
      for (int nt = 0; nt < 4; ++nt) {
        const bf16x8 vf =
            *(const bf16x8*)(Vb + (nt * 16 + l15) * 128 + ((ks * 64 + l4 * 16) ^ xr));
        o[nt] = __builtin_amdgcn_mfma_f32_16x16x32_bf16(vf, pf[ks], o[nt], 0, 0, 0);
      }
    __builtin_amdgcn_s_setprio(0);

    __builtin_amdgcn_s_barrier();
    asm volatile("" ::: "memory");
    cur ^= 1;
  }

  l_ += __shfl_xor(l_, 16);
  l_ += __shfl_xor(l_, 32);
  const float inv = 1.0f / l_;
  const int b = bh >> 4, h = bh & 15;
  const int q = q0 + l15;
#pragma unroll
  for (int nt = 0; nt < 4; ++nt) {
    bf16x4 yv;
#pragma unroll
    for (int r = 0; r < 4; ++r) yv[r] = (__bf16)(o[nt][r] * inv);
    *(bf16x4*)(y + ((size_t)(b * kT + q)) * kC + h * kD + nt * 16 + l4 * 4) = yv;
  }
}

extern "C" void kernel_launch(void* const* d_in, const int* in_sizes, int n_in,
                              void* d_out, int out_size, void* d_ws, size_t ws_size,
                              hipStream_t stream) {
  const float* x = (const float*)d_in[0];
  const float* wqkv = (const float*)d_in[1];
  const float* wproj = (const float*)d_in[2];
  const float* pe = (const float*)d_in[3];

  char* ws = (char*)d_ws;
  uint16_t* xp = (uint16_t*)(ws);                          // 8MB, reused as y
  uint16_t* wq = (uint16_t*)(ws + (size_t)(8u << 20));     // 6MB
  uint16_t* wp = (uint16_t*)(ws + (size_t)(14u << 20));    // 2MB
  uint16_t* qbuf = (uint16_t*)(ws + (size_t)(16u << 20));  // 8MB
  uint16_t* kbuf = (uint16_t*)(ws + (size_t)(24u << 20));  // 8MB
  uint16_t* vTb = (uint16_t*)(ws + (size_t)(32u << 20));   // 8MB (total 40MB)

  prep_all<<<dim3(8192), 256, 0, stream>>>(x, pe, wqkv, wproj, xp, wq, wp);

  // qkv = xp @ wqkv^T : M=4096, N=3072 (256^2 tiles, 192 blocks, 4-phase)
  gemm_qkv<<<dim3(192), 512, 0, stream>>>(xp, wq, qbuf, kbuf, vTb);

  // attention -> y (stored into xp buffer, [B,T,C] bf16)
  attn<<<dim3(kB * kH, kT / 64), 256, 0, stream>>>(qbuf, kbuf, vTb, xp);

  // out = y @ wproj^T : M=4096, N=1024, f32 out
  gemm_proj<<<dim3(32, 8), 256, 0, stream>>>(xp, wp, (float*)d_out);
}